// Round 1
// baseline (1568.890 us; speedup 1.0000x reference)
//
#include <hip/hip_runtime.h>
#include <hip/hip_bf16.h>

#define NNODES 98304
#define NB 4

__device__ __forceinline__ float bf2f(unsigned short u) {
  union { unsigned int u; float f; } c; c.u = ((unsigned int)u) << 16; return c.f;
}
__device__ __forceinline__ unsigned short f2bf(float f) {
  union { float f; unsigned int u; } c; c.f = f;
  unsigned int r = 0x7FFFu + ((c.u >> 16) & 1u);
  return (unsigned short)((c.u + r) >> 16);
}
__device__ __forceinline__ void fma4(float4& a, float s, const float4& w) {
  a.x = fmaf(s, w.x, a.x);
  a.y = fmaf(s, w.y, a.y);
  a.z = fmaf(s, w.z, a.z);
  a.w = fmaf(s, w.w, a.w);
}

// SAGE layer: out[row] = X[row]@Ws + mean4nbr(X)[row]@Wn + b, optional relu.
// Rows are (node n, batch b) pairs, M = NNODES*NB.
// SRCK: 0 = fp32 in [B, N, FIN] layout (harness input), 1 = bf16 in [N, B, stride] with col offset.
// DSTK: 0 = fp32 out [B, N, FOUT] (harness output), 1 = bf16 [N, B, stride] with col offset.
template<int FIN, int FOUT, int SRCK, int DSTK, bool RELU>
__global__ __launch_bounds__(256)
void sage_layer(const void* __restrict__ srcp, int sstride, int soff,
                void* __restrict__ dstp, int dstride, int doff,
                const float* __restrict__ Ws, const float* __restrict__ Wn,
                const float* __restrict__ bias, const int* __restrict__ nbr)
{
  constexpr int ROWS = 32;              // rows per block = 8 nodes * 4 batch
  constexpr int NT = ROWS / NB;         // nodes per block
  constexpr int LD = FIN + 4;           // pad to avoid LDS bank conflicts
  __shared__ float Xs[ROWS][LD];
  __shared__ float Ms[ROWS][LD];

  const int tid = threadIdx.x;
  const int node0 = blockIdx.x * NT;

  // ---- stage self row + 4-neighbor mean into LDS (vectorized 4-wide) ----
  constexpr int KQ = FIN / 4;
  constexpr int GROUPS = ROWS * KQ;
  for (int g = tid; g < GROUPS; g += 256) {
    const int r = g / KQ;
    const int k = (g - r * KQ) * 4;
    const int n = node0 + (r >> 2);
    const int b = r & 3;
    const int4 nb = reinterpret_cast<const int4*>(nbr)[n];
    float4 xv, m0, m1, m2, m3;
    if (SRCK == 0) {
      const float* s = (const float*)srcp;
      auto ld = [&](int nn) {
        return *reinterpret_cast<const float4*>(s + ((size_t)b * NNODES + nn) * FIN + k);
      };
      xv = ld(n); m0 = ld(nb.x); m1 = ld(nb.y); m2 = ld(nb.z); m3 = ld(nb.w);
    } else {
      const unsigned short* s = (const unsigned short*)srcp;
      auto ld = [&](int nn) {
        ushort4 u = *reinterpret_cast<const ushort4*>(s + ((size_t)nn * NB + b) * sstride + soff + k);
        return make_float4(bf2f(u.x), bf2f(u.y), bf2f(u.z), bf2f(u.w));
      };
      xv = ld(n); m0 = ld(nb.x); m1 = ld(nb.y); m2 = ld(nb.z); m3 = ld(nb.w);
    }
    float4 mv;
    mv.x = (m0.x + m1.x + m2.x + m3.x) * 0.25f;
    mv.y = (m0.y + m1.y + m2.y + m3.y) * 0.25f;
    mv.z = (m0.z + m1.z + m2.z + m3.z) * 0.25f;
    mv.w = (m0.w + m1.w + m2.w + m3.w) * 0.25f;
    *reinterpret_cast<float4*>(&Xs[r][k]) = xv;
    *reinterpret_cast<float4*>(&Ms[r][k]) = mv;
  }
  __syncthreads();

  // ---- compute: each thread owns 4 consecutive f_out for R rows ----
  constexpr int FG = FOUT / 4;          // f-groups
  constexpr int RS = 256 / FG;          // row stride between a thread's rows
  constexpr int R  = ROWS / RS;         // rows per thread (4/2/1)
  const int f0 = (tid % FG) * 4;
  const int r0 = tid / FG;

  float4 acc[R];
  const float4 bv = *reinterpret_cast<const float4*>(bias + f0);
  #pragma unroll
  for (int s = 0; s < R; ++s) acc[s] = bv;

  for (int k0 = 0; k0 < FIN; k0 += 4) {
    float4 ws[4], wn[4];
    #pragma unroll
    for (int j = 0; j < 4; ++j) {
      ws[j] = *reinterpret_cast<const float4*>(Ws + (size_t)(k0 + j) * FOUT + f0);
      wn[j] = *reinterpret_cast<const float4*>(Wn + (size_t)(k0 + j) * FOUT + f0);
    }
    #pragma unroll
    for (int s = 0; s < R; ++s) {
      const int r = r0 + s * RS;
      const float4 xv = *reinterpret_cast<const float4*>(&Xs[r][k0]);
      const float4 mv = *reinterpret_cast<const float4*>(&Ms[r][k0]);
      fma4(acc[s], xv.x, ws[0]); fma4(acc[s], mv.x, wn[0]);
      fma4(acc[s], xv.y, ws[1]); fma4(acc[s], mv.y, wn[1]);
      fma4(acc[s], xv.z, ws[2]); fma4(acc[s], mv.z, wn[2]);
      fma4(acc[s], xv.w, ws[3]); fma4(acc[s], mv.w, wn[3]);
    }
  }

  // ---- store ----
  #pragma unroll
  for (int s = 0; s < R; ++s) {
    const int r = r0 + s * RS;
    const int n = node0 + (r >> 2);
    const int b = r & 3;
    float4 v = acc[s];
    if (RELU) {
      v.x = fmaxf(v.x, 0.f); v.y = fmaxf(v.y, 0.f);
      v.z = fmaxf(v.z, 0.f); v.w = fmaxf(v.w, 0.f);
    }
    if (DSTK == 0) {
      float* d = (float*)dstp;
      *reinterpret_cast<float4*>(d + ((size_t)b * NNODES + n) * FOUT + f0) = v;
    } else {
      unsigned short* d = (unsigned short*)dstp;
      ushort4 u = make_ushort4(f2bf(v.x), f2bf(v.y), f2bf(v.z), f2bf(v.w));
      *reinterpret_cast<ushort4*>(d + ((size_t)n * NB + b) * dstride + doff + f0) = u;
    }
  }
}

extern "C" void kernel_launch(void* const* d_in, const int* in_sizes, int n_in,
                              void* d_out, int out_size, void* d_ws, size_t ws_size,
                              hipStream_t stream) {
  const float* x  = (const float*)d_in[0];   // [B, N, 64] fp32
  const int* nbr  = (const int*)d_in[1];     // [N, 4] int32
  const float* W1s = (const float*)d_in[2],  *W1n = (const float*)d_in[3],  *b1 = (const float*)d_in[4];
  const float* W2s = (const float*)d_in[5],  *W2n = (const float*)d_in[6],  *b2 = (const float*)d_in[7];
  const float* W3s = (const float*)d_in[8],  *W3n = (const float*)d_in[9],  *b3 = (const float*)d_in[10];
  const float* W4s = (const float*)d_in[11], *W4n = (const float*)d_in[12], *b4 = (const float*)d_in[13];
  const float* W5s = (const float*)d_in[14], *W5n = (const float*)d_in[15], *b5 = (const float*)d_in[16];
  const float* W6s = (const float*)d_in[17], *W6n = (const float*)d_in[18], *b6 = (const float*)d_in[19];

  // Buffers (bf16 intermediates):
  //   h1   [N,B,128] bf16  -> lives in d_out (exactly out bytes), dead after L2
  //   h6buf[N,B,128] bf16  -> d_ws (h2 in cols 64:128, sage(h5) in cols 0:64)
  //   h5buf[N,B, 64] bf16  -> d_out offset 0 (h3 in cols 32:64, sage(h4) in cols 0:32)
  //   h4   [N,B, 32] bf16  -> d_out offset 50.33MB
  unsigned short* h1 = (unsigned short*)d_out;
  unsigned short* h6 = (unsigned short*)d_ws;
  unsigned short* h5 = (unsigned short*)d_out;
  unsigned short* h4 = (unsigned short*)((char*)d_out + (size_t)NNODES * NB * 64 * 2);

  const dim3 grid(NNODES / 8), block(256);

  // L1: x(fp32,[B,N,64]) -> h1 [*,128]
  sage_layer<64, 128, 0, 1, true><<<grid, block, 0, stream>>>(x, 0, 0, h1, 128, 0, W1s, W1n, b1, nbr);
  // L2: h1 -> h2 = h6buf cols 64:128
  sage_layer<128, 64, 1, 1, true><<<grid, block, 0, stream>>>(h1, 128, 0, h6, 128, 64, W2s, W2n, b2, nbr);
  // L3: h2 -> h3 = h5buf cols 32:64
  sage_layer<64, 32, 1, 1, true><<<grid, block, 0, stream>>>(h6, 128, 64, h5, 64, 32, W3s, W3n, b3, nbr);
  // L4: h3 -> h4
  sage_layer<32, 32, 1, 1, true><<<grid, block, 0, stream>>>(h5, 64, 32, h4, 32, 0, W4s, W4n, b4, nbr);
  // L5: h4 -> h5buf cols 0:32 (reuses layer-4 weights, per reference)
  sage_layer<32, 32, 1, 1, true><<<grid, block, 0, stream>>>(h4, 32, 0, h5, 64, 0, W4s, W4n, b4, nbr);
  // L6: h5 (64) -> h6buf cols 0:64
  sage_layer<64, 64, 1, 1, true><<<grid, block, 0, stream>>>(h5, 64, 0, h6, 128, 0, W5s, W5n, b5, nbr);
  // L7: h6 (128) -> out fp32 [B,N,64], no relu
  sage_layer<128, 64, 1, 0, false><<<grid, block, 0, stream>>>(h6, 128, 0, d_out, 0, 0, W6s, W6n, b6, nbr);
}

// Round 2
// 276.787 us; speedup vs baseline: 5.6682x; 5.6682x over previous
//
#include <hip/hip_runtime.h>

#define NNODES 98304
#define NB 4

typedef __attribute__((ext_vector_type(8))) short short8;
typedef __attribute__((ext_vector_type(8))) unsigned short ushort8;
typedef __attribute__((ext_vector_type(4))) float f32x4;

__device__ __forceinline__ float bf2f(unsigned short u) {
  union { unsigned int u; float f; } c; c.u = ((unsigned int)u) << 16; return c.f;
}
__device__ __forceinline__ unsigned short f2bf(float f) {
  union { float f; unsigned int u; } c; c.f = f;
  unsigned int r = 0x7FFFu + ((c.u >> 16) & 1u);
  return (unsigned short)((c.u + r) >> 16);
}

// Fused SAGE layer via MFMA: out = relu?( [X | mean4(X)] @ [Ws; Wn] + b ).
// Rows are (node, batch) pairs, M = NNODES*NB. Block = 64 rows (16 nodes).
// SRCK: 0 = fp32 [B, N, FIN] (harness input); 1 = bf16 [N, B, sstride] + col offset soff.
// DSTK: 0 = fp32 [B, N, FOUT] (harness output); 1 = bf16 [N, B, dstride] + doff.
template<int FIN, int FOUT, int SRCK, int DSTK, bool RELU>
__global__ __launch_bounds__(256)
void sage_mfma(const void* __restrict__ srcp, int sstride, int soff,
               void* __restrict__ dstp, int dstride, int doff,
               const float* __restrict__ Ws, const float* __restrict__ Wn,
               const float* __restrict__ bias, const int* __restrict__ nbr)
{
  constexpr int K = 2 * FIN;                 // fused K: self | mean
  constexpr int KSTEPS = K / 32;
  constexpr int LD = K + 8;                  // +16B pad -> 4-bank row skew (2-way max, free)
  constexpr int WAVES_N = (FOUT >= 64) ? 4 : 2;
  constexpr int WAVES_M = 4 / WAVES_N;
  constexpr int CF = FOUT / (16 * WAVES_N);  // col frags per wave
  constexpr int RF = 64 / (16 * WAVES_M);    // row frags per wave

  __shared__ unsigned short As[64][LD];

  const int tid = threadIdx.x;
  const int node0 = blockIdx.x * 16;

  // ---- stage [self | mean of 4 neighbors] into LDS as bf16 ----
  constexpr int CHUNKS = FIN / 8;
  constexpr int ITERS = (64 * CHUNKS) / 256;   // 4 / 2 / 1
  #pragma unroll
  for (int it = 0; it < ITERS; ++it) {
    const int g = tid + it * 256;
    const int r = g / CHUNKS;
    const int c = (g - r * CHUNKS) * 8;
    const int n = node0 + (r >> 2);
    const int b = r & 3;
    const int4 nb4 = reinterpret_cast<const int4*>(nbr)[n];
    ushort8 xv, mv;
    if (SRCK == 0) {
      const float* s = (const float*)srcp;
      const float* ps = s + ((size_t)b * NNODES + n) * FIN + c;
      const float* p0 = s + ((size_t)b * NNODES + nb4.x) * FIN + c;
      const float* p1 = s + ((size_t)b * NNODES + nb4.y) * FIN + c;
      const float* p2 = s + ((size_t)b * NNODES + nb4.z) * FIN + c;
      const float* p3 = s + ((size_t)b * NNODES + nb4.w) * FIN + c;
      #pragma unroll
      for (int j = 0; j < 8; ++j) {
        xv[j] = f2bf(ps[j]);
        mv[j] = f2bf((p0[j] + p1[j] + p2[j] + p3[j]) * 0.25f);
      }
    } else {
      const unsigned short* s = (const unsigned short*)srcp;
      auto ld = [&](int nn) {
        return *reinterpret_cast<const ushort8*>(s + ((size_t)nn * NB + b) * sstride + soff + c);
      };
      xv = ld(n);
      const ushort8 a0 = ld(nb4.x), a1 = ld(nb4.y), a2 = ld(nb4.z), a3 = ld(nb4.w);
      #pragma unroll
      for (int j = 0; j < 8; ++j)
        mv[j] = f2bf((bf2f(a0[j]) + bf2f(a1[j]) + bf2f(a2[j]) + bf2f(a3[j])) * 0.25f);
    }
    *reinterpret_cast<ushort8*>(&As[r][c]) = xv;
    *reinterpret_cast<ushort8*>(&As[r][FIN + c]) = mv;
  }

  // ---- B fragments (combined [Ws; Wn], fp32 -> bf16) held in registers ----
  const int wave = tid >> 6;
  const int lane = tid & 63;
  const int wn = wave % WAVES_N;
  const int wm = wave / WAVES_N;
  const int colbase = wn * (FOUT / WAVES_N);
  const int rowbase = wm * (64 / WAVES_M);
  const int fn = lane & 15;
  const int fg = lane >> 4;

  short8 Bfrag[KSTEPS][CF];
  #pragma unroll
  for (int ks = 0; ks < KSTEPS; ++ks) {
    const float* wb = (ks * 32 < FIN) ? (Ws + (size_t)(ks * 32) * FOUT)
                                      : (Wn + (size_t)(ks * 32 - FIN) * FOUT);
    #pragma unroll
    for (int cf = 0; cf < CF; ++cf) {
      const int col = colbase + cf * 16 + fn;
      short8 f;
      #pragma unroll
      for (int j = 0; j < 8; ++j)
        f[j] = (short)f2bf(wb[(size_t)(fg * 8 + j) * FOUT + col]);
      Bfrag[ks][cf] = f;
    }
  }

  f32x4 acc[RF][CF];
  #pragma unroll
  for (int rf = 0; rf < RF; ++rf)
    #pragma unroll
    for (int cf = 0; cf < CF; ++cf) {
      const float bv = bias[colbase + cf * 16 + fn];
      acc[rf][cf] = (f32x4){bv, bv, bv, bv};
    }

  __syncthreads();

  // ---- K loop: ds_read_b128 A frags + MFMA ----
  #pragma unroll
  for (int ks = 0; ks < KSTEPS; ++ks) {
    short8 a[RF];
    #pragma unroll
    for (int rf = 0; rf < RF; ++rf)
      a[rf] = *reinterpret_cast<const short8*>(&As[rowbase + rf * 16 + fn][ks * 32 + fg * 8]);
    #pragma unroll
    for (int rf = 0; rf < RF; ++rf)
      #pragma unroll
      for (int cf = 0; cf < CF; ++cf)
        acc[rf][cf] = __builtin_amdgcn_mfma_f32_16x16x32_bf16(
            a[rf], Bfrag[ks][cf], acc[rf][cf], 0, 0, 0);
  }

  // ---- store (C/D map: col = lane&15, row = (lane>>4)*4 + j) ----
  #pragma unroll
  for (int rf = 0; rf < RF; ++rf) {
    #pragma unroll
    for (int cf = 0; cf < CF; ++cf) {
      const int col = colbase + cf * 16 + fn;
      #pragma unroll
      for (int j = 0; j < 4; ++j) {
        const int row = rowbase + rf * 16 + fg * 4 + j;
        const int n = node0 + (row >> 2);
        const int b = row & 3;
        float v = acc[rf][cf][j];
        if (RELU) v = fmaxf(v, 0.f);
        if (DSTK == 0) {
          ((float*)dstp)[((size_t)b * NNODES + n) * FOUT + col] = v;
        } else {
          ((unsigned short*)dstp)[((size_t)n * NB + b) * dstride + doff + col] = f2bf(v);
        }
      }
    }
  }
}

extern "C" void kernel_launch(void* const* d_in, const int* in_sizes, int n_in,
                              void* d_out, int out_size, void* d_ws, size_t ws_size,
                              hipStream_t stream) {
  const float* x  = (const float*)d_in[0];   // [B, N, 64] fp32
  const int* nbr  = (const int*)d_in[1];     // [N, 4] int32
  const float* W1s = (const float*)d_in[2],  *W1n = (const float*)d_in[3],  *b1 = (const float*)d_in[4];
  const float* W2s = (const float*)d_in[5],  *W2n = (const float*)d_in[6],  *b2 = (const float*)d_in[7];
  const float* W3s = (const float*)d_in[8],  *W3n = (const float*)d_in[9],  *b3 = (const float*)d_in[10];
  const float* W4s = (const float*)d_in[11], *W4n = (const float*)d_in[12], *b4 = (const float*)d_in[13];
  const float* W5s = (const float*)d_in[14], *W5n = (const float*)d_in[15], *b5 = (const float*)d_in[16];
  const float* W6s = (const float*)d_in[17], *W6n = (const float*)d_in[18], *b6 = (const float*)d_in[19];

  // Buffers (bf16 intermediates):
  //   h1   [N,B,128] bf16  -> d_out (exactly out bytes), dead after L2
  //   h6buf[N,B,128] bf16  -> d_ws   (h2 in cols 64:128, sage6-out in cols 0:64)
  //   h5buf[N,B, 64] bf16  -> d_out  (h3 in cols 32:64, sage5-out in cols 0:32)
  //   h4   [N,B, 32] bf16  -> d_out + 50.33MB
  unsigned short* h1 = (unsigned short*)d_out;
  unsigned short* h6 = (unsigned short*)d_ws;
  unsigned short* h5 = (unsigned short*)d_out;
  unsigned short* h4 = (unsigned short*)((char*)d_out + (size_t)NNODES * NB * 64 * 2);

  const dim3 grid(NNODES * NB / 64), block(256);

  // L1: x(fp32) -> h1 [*,128]
  sage_mfma<64, 128, 0, 1, true><<<grid, block, 0, stream>>>(x, 0, 0, h1, 128, 0, W1s, W1n, b1, nbr);
  // L2: h1 -> h2 = h6buf cols 64:128
  sage_mfma<128, 64, 1, 1, true><<<grid, block, 0, stream>>>(h1, 128, 0, h6, 128, 64, W2s, W2n, b2, nbr);
  // L3: h2 -> h3 = h5buf cols 32:64
  sage_mfma<64, 32, 1, 1, true><<<grid, block, 0, stream>>>(h6, 128, 64, h5, 64, 32, W3s, W3n, b3, nbr);
  // L4: h3 -> h4
  sage_mfma<32, 32, 1, 1, true><<<grid, block, 0, stream>>>(h5, 64, 32, h4, 32, 0, W4s, W4n, b4, nbr);
  // L5: h4 -> h5buf cols 0:32 (layer-4 weights reused, per reference)
  sage_mfma<32, 32, 1, 1, true><<<grid, block, 0, stream>>>(h4, 32, 0, h5, 64, 0, W4s, W4n, b4, nbr);
  // L6: h5 -> h6buf cols 0:64
  sage_mfma<64, 64, 1, 1, true><<<grid, block, 0, stream>>>(h5, 64, 0, h6, 128, 0, W5s, W5n, b5, nbr);
  // L7: h6 -> out fp32 [B,N,64], no relu
  sage_mfma<128, 64, 1, 0, false><<<grid, block, 0, stream>>>(h6, 128, 0, d_out, 0, 0, W6s, W6n, b6, nbr);
}

// Round 3
// 250.523 us; speedup vs baseline: 6.2625x; 1.1048x over previous
//
#include <hip/hip_runtime.h>

#define NNODES 98304
#define NB 4
#define NTILES ((NNODES * NB) / 64)   // 6144 tiles of 64 rows
#define GRID_BLOCKS 1024              // persistent-ish: 6 tiles per block, 4 blocks/CU

typedef __attribute__((ext_vector_type(8))) short short8;
typedef __attribute__((ext_vector_type(8))) unsigned short ushort8;
typedef __attribute__((ext_vector_type(4))) float f32x4;

__device__ __forceinline__ float bf2f(unsigned short u) {
  union { unsigned int u; float f; } c; c.u = ((unsigned int)u) << 16; return c.f;
}
__device__ __forceinline__ unsigned short f2bf(float f) {
  union { float f; unsigned int u; } c; c.f = f;
  unsigned int r = 0x7FFFu + ((c.u >> 16) & 1u);
  return (unsigned short)((c.u + r) >> 16);
}
// packed f32x2 -> bf16x2 (RNE), single VALU op
__device__ __forceinline__ unsigned int cvtpk(float lo, float hi) {
  unsigned int r;
  asm("v_cvt_pk_bf16_f32 %0, %1, %2" : "=v"(r) : "v"(lo), "v"(hi));
  return r;
}

// Fused SAGE layer via MFMA: out = relu?( [X | mean4(X)] @ [Ws; Wn] + b ).
// Rows are (node, batch) pairs, M = NNODES*NB. Tile = 64 rows (16 nodes).
// Persistent blocks: B-fragments (weights, bf16) built once, tiles grid-strided.
// SRCK: 0 = fp32 [B, N, FIN]; 1 = bf16 [N, B, sstride] + col offset soff.
// DSTK: 0 = fp32 [B, N, FOUT]; 1 = bf16 [N, B, dstride] + doff.
template<int FIN, int FOUT, int SRCK, int DSTK, bool RELU>
__global__ __launch_bounds__(256, 4)
void sage_mfma(const void* __restrict__ srcp, int sstride, int soff,
               void* __restrict__ dstp, int dstride, int doff,
               const float* __restrict__ Ws, const float* __restrict__ Wn,
               const float* __restrict__ bias, const int* __restrict__ nbr)
{
  constexpr int K = 2 * FIN;                 // fused K: self | mean
  constexpr int KSTEPS = K / 32;
  constexpr int LD = K + 8;                  // +16B pad -> skewed rows (2-way max, free)
  constexpr int WAVES_N = (FOUT >= 64) ? 4 : 2;
  constexpr int WAVES_M = 4 / WAVES_N;
  constexpr int CF = FOUT / (16 * WAVES_N);  // col frags per wave
  constexpr int RF = 64 / (16 * WAVES_M);    // row frags per wave

  __shared__ unsigned short As[64][LD];

  const int tid = threadIdx.x;
  const int wave = tid >> 6;
  const int lane = tid & 63;
  const int wn = wave % WAVES_N;
  const int wm = wave / WAVES_N;
  const int colbase = wn * (FOUT / WAVES_N);
  const int rowbase = wm * (64 / WAVES_M);
  const int fn = lane & 15;
  const int fg = lane >> 4;

  // ---- B fragments (combined [Ws; Wn], fp32 -> bf16): built ONCE ----
  short8 Bfrag[KSTEPS][CF];
  float bv[CF];
  #pragma unroll
  for (int ks = 0; ks < KSTEPS; ++ks) {
    const float* wb = (ks * 32 < FIN) ? (Ws + (size_t)(ks * 32) * FOUT)
                                      : (Wn + (size_t)(ks * 32 - FIN) * FOUT);
    #pragma unroll
    for (int cf = 0; cf < CF; ++cf) {
      const int col = colbase + cf * 16 + fn;
      short8 f;
      #pragma unroll
      for (int j = 0; j < 8; ++j)
        f[j] = (short)f2bf(wb[(size_t)(fg * 8 + j) * FOUT + col]);
      Bfrag[ks][cf] = f;
    }
  }
  #pragma unroll
  for (int cf = 0; cf < CF; ++cf) bv[cf] = bias[colbase + cf * 16 + fn];

  // ---- persistent tile loop ----
  for (int tile = blockIdx.x; tile < NTILES; tile += GRID_BLOCKS) {
    const int node0 = tile * 16;

    // ---- stage [self | mean4] into LDS as bf16 ----
    constexpr int CHUNKS = FIN / 8;
    constexpr int ITERS = (64 * CHUNKS) / 256;   // 4 / 2 / 1
    #pragma unroll
    for (int it = 0; it < ITERS; ++it) {
      const int g = tid + it * 256;
      const int r = g / CHUNKS;
      const int c = (g - r * CHUNKS) * 8;
      const int n = node0 + (r >> 2);
      const int b = r & 3;
      const int4 nb4 = reinterpret_cast<const int4*>(nbr)[n];
      uint4 xv, mv;
      if (SRCK == 0) {
        const float* s = (const float*)srcp;
        const float* ps = s + ((size_t)b * NNODES + n) * FIN + c;
        const float* p0 = s + ((size_t)b * NNODES + nb4.x) * FIN + c;
        const float* p1 = s + ((size_t)b * NNODES + nb4.y) * FIN + c;
        const float* p2 = s + ((size_t)b * NNODES + nb4.z) * FIN + c;
        const float* p3 = s + ((size_t)b * NNODES + nb4.w) * FIN + c;
        float4 sa = *(const float4*)ps,        sb = *(const float4*)(ps + 4);
        float4 a0 = *(const float4*)p0,        b0 = *(const float4*)(p0 + 4);
        float4 a1 = *(const float4*)p1,        b1 = *(const float4*)(p1 + 4);
        float4 a2 = *(const float4*)p2,        b2 = *(const float4*)(p2 + 4);
        float4 a3 = *(const float4*)p3,        b3 = *(const float4*)(p3 + 4);
        xv = make_uint4(cvtpk(sa.x, sa.y), cvtpk(sa.z, sa.w),
                        cvtpk(sb.x, sb.y), cvtpk(sb.z, sb.w));
        float4 m0, m1;
        m0.x = (a0.x + a1.x) + (a2.x + a3.x); m0.y = (a0.y + a1.y) + (a2.y + a3.y);
        m0.z = (a0.z + a1.z) + (a2.z + a3.z); m0.w = (a0.w + a1.w) + (a2.w + a3.w);
        m1.x = (b0.x + b1.x) + (b2.x + b3.x); m1.y = (b0.y + b1.y) + (b2.y + b3.y);
        m1.z = (b0.z + b1.z) + (b2.z + b3.z); m1.w = (b0.w + b1.w) + (b2.w + b3.w);
        mv = make_uint4(cvtpk(m0.x * 0.25f, m0.y * 0.25f), cvtpk(m0.z * 0.25f, m0.w * 0.25f),
                        cvtpk(m1.x * 0.25f, m1.y * 0.25f), cvtpk(m1.z * 0.25f, m1.w * 0.25f));
      } else {
        const unsigned short* s = (const unsigned short*)srcp;
        auto ld = [&](int nn) {
          return *reinterpret_cast<const ushort8*>(s + ((size_t)nn * NB + b) * sstride + soff + c);
        };
        const ushort8 sv = ld(n);
        xv = make_uint4((unsigned)sv[0] | ((unsigned)sv[1] << 16),
                        (unsigned)sv[2] | ((unsigned)sv[3] << 16),
                        (unsigned)sv[4] | ((unsigned)sv[5] << 16),
                        (unsigned)sv[6] | ((unsigned)sv[7] << 16));
        const ushort8 a0 = ld(nb4.x), a1 = ld(nb4.y), a2 = ld(nb4.z), a3 = ld(nb4.w);
        float sum[8];
        #pragma unroll
        for (int j = 0; j < 8; ++j)
          sum[j] = (bf2f(a0[j]) + bf2f(a1[j])) + (bf2f(a2[j]) + bf2f(a3[j]));
        mv = make_uint4(cvtpk(sum[0] * 0.25f, sum[1] * 0.25f), cvtpk(sum[2] * 0.25f, sum[3] * 0.25f),
                        cvtpk(sum[4] * 0.25f, sum[5] * 0.25f), cvtpk(sum[6] * 0.25f, sum[7] * 0.25f));
      }
      *reinterpret_cast<uint4*>(&As[r][c]) = xv;
      *reinterpret_cast<uint4*>(&As[r][FIN + c]) = mv;
    }
    __syncthreads();

    // ---- K loop: ds_read_b128 A frags + MFMA ----
    f32x4 acc[RF][CF];
    #pragma unroll
    for (int rf = 0; rf < RF; ++rf)
      #pragma unroll
      for (int cf = 0; cf < CF; ++cf)
        acc[rf][cf] = (f32x4){bv[cf], bv[cf], bv[cf], bv[cf]};

    #pragma unroll
    for (int ks = 0; ks < KSTEPS; ++ks) {
      short8 a[RF];
      #pragma unroll
      for (int rf = 0; rf < RF; ++rf)
        a[rf] = *reinterpret_cast<const short8*>(&As[rowbase + rf * 16 + fn][ks * 32 + fg * 8]);
      #pragma unroll
      for (int rf = 0; rf < RF; ++rf)
        #pragma unroll
        for (int cf = 0; cf < CF; ++cf)
          acc[rf][cf] = __builtin_amdgcn_mfma_f32_16x16x32_bf16(
              a[rf], Bfrag[ks][cf], acc[rf][cf], 0, 0, 0);
    }
    __syncthreads();   // As consumed; safe to restage next tile

    // ---- store (C/D map: col = lane&15, row = (lane>>4)*4 + j) ----
    #pragma unroll
    for (int rf = 0; rf < RF; ++rf) {
      #pragma unroll
      for (int cf = 0; cf < CF; ++cf) {
        const int col = colbase + cf * 16 + fn;
        #pragma unroll
        for (int j = 0; j < 4; ++j) {
          const int row = rowbase + rf * 16 + fg * 4 + j;
          const int n = node0 + (row >> 2);
          const int b = row & 3;
          float v = acc[rf][cf][j];
          if (RELU) v = fmaxf(v, 0.f);
          if (DSTK == 0) {
            ((float*)dstp)[((size_t)b * NNODES + n) * FOUT + col] = v;
          } else {
            ((unsigned short*)dstp)[((size_t)n * NB + b) * dstride + doff + col] = f2bf(v);
          }
        }
      }
    }
  }
}

extern "C" void kernel_launch(void* const* d_in, const int* in_sizes, int n_in,
                              void* d_out, int out_size, void* d_ws, size_t ws_size,
                              hipStream_t stream) {
  const float* x  = (const float*)d_in[0];   // [B, N, 64] fp32
  const int* nbr  = (const int*)d_in[1];     // [N, 4] int32
  const float* W1s = (const float*)d_in[2],  *W1n = (const float*)d_in[3],  *b1 = (const float*)d_in[4];
  const float* W2s = (const float*)d_in[5],  *W2n = (const float*)d_in[6],  *b2 = (const float*)d_in[7];
  const float* W3s = (const float*)d_in[8],  *W3n = (const float*)d_in[9],  *b3 = (const float*)d_in[10];
  const float* W4s = (const float*)d_in[11], *W4n = (const float*)d_in[12], *b4 = (const float*)d_in[13];
  const float* W5s = (const float*)d_in[14], *W5n = (const float*)d_in[15], *b5 = (const float*)d_in[16];
  const float* W6s = (const float*)d_in[17], *W6n = (const float*)d_in[18], *b6 = (const float*)d_in[19];

  // Buffers (bf16 intermediates):
  //   h1   [N,B,128] bf16  -> d_out (exactly out bytes), dead after L2
  //   h6buf[N,B,128] bf16  -> d_ws   (h2 in cols 64:128, sage6-out in cols 0:64)
  //   h5buf[N,B, 64] bf16  -> d_out  (h3 in cols 32:64, sage5-out in cols 0:32)
  //   h4   [N,B, 32] bf16  -> d_out + 50.33MB
  unsigned short* h1 = (unsigned short*)d_out;
  unsigned short* h6 = (unsigned short*)d_ws;
  unsigned short* h5 = (unsigned short*)d_out;
  unsigned short* h4 = (unsigned short*)((char*)d_out + (size_t)NNODES * NB * 64 * 2);

  const dim3 grid(GRID_BLOCKS), block(256);

  // L1: x(fp32) -> h1 [*,128]
  sage_mfma<64, 128, 0, 1, true><<<grid, block, 0, stream>>>(x, 0, 0, h1, 128, 0, W1s, W1n, b1, nbr);
  // L2: h1 -> h2 = h6buf cols 64:128
  sage_mfma<128, 64, 1, 1, true><<<grid, block, 0, stream>>>(h1, 128, 0, h6, 128, 64, W2s, W2n, b2, nbr);
  // L3: h2 -> h3 = h5buf cols 32:64
  sage_mfma<64, 32, 1, 1, true><<<grid, block, 0, stream>>>(h6, 128, 64, h5, 64, 32, W3s, W3n, b3, nbr);
  // L4: h3 -> h4
  sage_mfma<32, 32, 1, 1, true><<<grid, block, 0, stream>>>(h5, 64, 32, h4, 32, 0, W4s, W4n, b4, nbr);
  // L5: h4 -> h5buf cols 0:32 (layer-4 weights reused, per reference)
  sage_mfma<32, 32, 1, 1, true><<<grid, block, 0, stream>>>(h4, 32, 0, h5, 64, 0, W4s, W4n, b4, nbr);
  // L6: h5 -> h6buf cols 0:64
  sage_mfma<64, 64, 1, 1, true><<<grid, block, 0, stream>>>(h5, 64, 0, h6, 128, 0, W5s, W5n, b5, nbr);
  // L7: h6 -> out fp32 [B,N,64], no relu
  sage_mfma<128, 64, 1, 0, false><<<grid, block, 0, stream>>>(h6, 128, 0, d_out, 0, 0, W6s, W6n, b6, nbr);
}